// Round 5
// baseline (537.767 us; speedup 1.0000x reference)
//
#include <hip/hip_runtime.h>

#define NUM_LEARNERS 50000
#define NUM_SCENES   2000
#define EMBED_DIM    128
#define HID          16
#define GRID_BLOCKS  2048   // 8192 persistent waves, 6-7 rows each

// R9 = R8 (barrier-free R4, measured 523.3 vs R4's 521.4 = noise) made
// PERSISTENT: grid-stride over rows with 2048 blocks instead of 12500
// one-shot blocks. Targets the last untested residual: per-block launch/
// drain tail and per-wave constant setup (W1/b1/b2 loads, lane-role calc),
// now paid 8192x instead of 50000x, plus cross-row load/epilogue overlap
// within a wave. Per-row phases are byte-identical to R8.
//
// One wave per learner row. Algebra: sum_{j in nz} mlp[j] =
// W2^T (sum_{j in nz} h(j)) + count*b2, h(j)[k] = relu(j*W1[k]+b1[k]).
__global__ __launch_bounds__(256) void fused_gather_mean_kernel(
    const float* __restrict__ M,
    const float* __restrict__ W1, const float* __restrict__ b1,
    const float* __restrict__ W2, const float* __restrict__ b2,
    float* __restrict__ out)
{
    // 2048-entry rows: phase-2 reads groups of 4 up to index 2047 -> in-bounds.
    __shared__ unsigned short idxbuf[4][2048];         // 16384 B -> 8 blocks/CU
    const int wave = threadIdx.x >> 6;
    const int lane = threadIdx.x & 63;
    unsigned short* myidx = idxbuf[wave];

    // Lane roles for phase 2: group g = lane>>2 consumes 4 consecutive
    // indices per iteration; sub = lane&3 covers h-dims 4*sub..4*sub+3.
    const int g   = lane >> 2;
    const int sub = lane & 3;

    // ---- Per-wave constants, hoisted out of the row loop ----
    float w1v[4], b1v[4];
#pragma unroll
    for (int c = 0; c < 4; ++c) {
        w1v[c] = W1[4 * sub + c];
        b1v[c] = b1[4 * sub + c];
    }
    const float2 bv = ((const float2*)b2)[lane];
    const float2* __restrict__ W2v = (const float2*)W2;    // [16][64] float2

    const int gw0 = blockIdx.x * 4 + wave;                 // 8192 waves

    for (long row = gw0; row < NUM_LEARNERS; row += GRID_BLOCKS * 4) {
        const float4* __restrict__ M4 = (const float4*)(M + row * NUM_SCENES);

        // ---- Phase 0: prefetch the full row (8 independent dwordx4 loads)
        float4 v[8];
#pragma unroll
        for (int it = 0; it < 8; ++it) {
            int c4 = it * 64 + lane;                 // < 448 for it<7 (no branch)
            if (c4 < 500) v[it] = M4[c4];
            else          v[it] = make_float4(0.f, 0.f, 0.f, 0.f);
        }

        // ---- Phase 1: ballot-compaction of nonzero column indices ----
        int count = 0;
#pragma unroll
        for (int it = 0; it < 8; ++it) {
            int c4 = it * 64 + lane;
            float vals[4] = {v[it].x, v[it].y, v[it].z, v[it].w};
#pragma unroll
            for (int c = 0; c < 4; ++c) {
                bool nz = (vals[c] != 0.0f);
                unsigned long long m = __ballot(nz);
                if (nz) {
                    int below = __builtin_amdgcn_mbcnt_hi(
                        (unsigned)(m >> 32),
                        __builtin_amdgcn_mbcnt_lo((unsigned)m, 0));
                    myidx[count + below] = (unsigned short)(c4 * 4 + c);
                }
                count += __popcll(m);                // wave-uniform running total
            }
        }

        // No __syncthreads(): idxbuf[wave] is per-wave; same-wave ds ordering
        // is enforced by compiler-inserted s_waitcnt lgkmcnt.

        // ---- Phase 2: in-register h-sum, 64 indices per iteration ----
        float4 acc = make_float4(0.f, 0.f, 0.f, 0.f);
        const int nIter = (count + 63) >> 6;
        for (int t = 0; t < nIter; ++t) {
            int base = t * 64 + g * 4;               // group's 4 indices
            ushort4 idx4 = *(const ushort4*)&myidx[base];  // ds_read_b64
            const unsigned short* iq = (const unsigned short*)&idx4;
#pragma unroll
            for (int q = 0; q < 4; ++q) {
                float x    = (float)iq[q];
                float mval = (base + q < count) ? 1.0f : 0.0f;   // tail mask
#pragma unroll
                for (int c = 0; c < 4; ++c) {
                    float h = fmaxf(fmaf(x, w1v[c], b1v[c]), 0.0f);
                    (&acc.x)[c] = fmaf(h, mval, (&acc.x)[c]);
                }
            }
        }

        // Reduce across the 16 index-groups: butterfly over strides 4..32.
#pragma unroll
        for (int off = 4; off < 64; off <<= 1) {
            acc.x += __shfl_xor(acc.x, off);
            acc.y += __shfl_xor(acc.y, off);
            acc.z += __shfl_xor(acc.z, off);
            acc.w += __shfl_xor(acc.w, off);
        }
        // Lane l holds s[4*(l&3)+c]; broadcast all 16 to every lane.
        float s[HID];
#pragma unroll
        for (int a = 0; a < 4; ++a) {
            s[4 * a + 0] = __shfl(acc.x, a);
            s[4 * a + 1] = __shfl(acc.y, a);
            s[4 * a + 2] = __shfl(acc.z, a);
            s[4 * a + 3] = __shfl(acc.w, a);
        }

        // ---- Epilogue: emb[d] = (sum_k s[k]*W2[k][d] + cnt*b2[d]) / max(cnt,1)
        // Lane l owns dims 2l, 2l+1. W2 (8KB) / b2 (512B) are L1-hot.
        const float cnt = (float)count;
        const float inv = 1.0f / fmaxf(cnt, 1.0f);
        float e0 = cnt * bv.x;
        float e1 = cnt * bv.y;
#pragma unroll
        for (int k = 0; k < HID; ++k) {
            float2 w = W2v[k * 64 + lane];
            e0 = fmaf(s[k], w.x, e0);
            e1 = fmaf(s[k], w.y, e1);
        }
        ((float2*)out)[row * 64 + lane] = make_float2(e0 * inv, e1 * inv);
    }
}

extern "C" void kernel_launch(void* const* d_in, const int* in_sizes, int n_in,
                              void* d_out, int out_size, void* d_ws, size_t ws_size,
                              hipStream_t stream) {
    const float* M  = (const float*)d_in[0];   // [50000, 2000]
    const float* W1 = (const float*)d_in[1];   // [1, 16]
    const float* b1 = (const float*)d_in[2];   // [16]
    const float* W2 = (const float*)d_in[3];   // [16, 128]
    const float* b2 = (const float*)d_in[4];   // [128]
    float* out = (float*)d_out;                // [50000, 128]

    fused_gather_mean_kernel<<<GRID_BLOCKS, 256, 0, stream>>>(
        M, W1, b1, W2, b2, out);
}